// Round 1
// baseline (698.365 us; speedup 1.0000x reference)
//
#include <hip/hip_runtime.h>

#define B_  32
#define LC_ 2048
#define LQ_ 256
#define D_  256
#define NEG (-1e30f)

// ---------------- K1: sc = context . wc ; sq = query . wq ----------------
__global__ __launch_bounds__(256) void k_scsq(
    const float* __restrict__ ctx, const float* __restrict__ qry,
    const float* __restrict__ w0, float* __restrict__ sc, float* __restrict__ sq)
{
    const int lane = threadIdx.x & 63;
    const int wave = threadIdx.x >> 6;
    const int row  = blockIdx.x * 4 + wave;
    const int NC = B_ * LC_;
    const int NQ = B_ * LQ_;
    const float* src; const float* w; float* dst;
    if (row < NC) { src = ctx + (long long)row * D_; w = w0; dst = sc + row; }
    else if (row < NC + NQ) { int r = row - NC; src = qry + (long long)r * D_; w = w0 + D_; dst = sq + r; }
    else return;
    float4 a = *(const float4*)(src + lane * 4);
    float4 b = *(const float4*)(w   + lane * 4);
    float v = a.x*b.x + a.y*b.y + a.z*b.z + a.w*b.w;
    #pragma unroll
    for (int off = 32; off > 0; off >>= 1) v += __shfl_down(v, off, 64);
    if (lane == 0) *dst = v;
}

// ---------------- K2: sim[b,c,q] = sc+sq+sum_d ctx*wm*qry, masked ----------------
__global__ __launch_bounds__(256) void k_sim(
    const float* __restrict__ ctx, const float* __restrict__ qry,
    const int* __restrict__ cmask, const int* __restrict__ qmask,
    const float* __restrict__ w0, const float* __restrict__ sc,
    const float* __restrict__ sq, float* __restrict__ sim)
{
    __shared__ __align__(16) float As[32][68];  // [k][c]
    __shared__ __align__(16) float Bs[32][68];  // [k][q]
    const int b  = blockIdx.z;
    const int c0 = blockIdx.x * 64;
    const int q0 = blockIdx.y * 64;
    const int t  = threadIdx.x;
    const int tx = t & 15, ty = t >> 4;
    const float* wm = w0 + 2 * D_;
    const float* Abase = ctx + (long long)b * LC_ * D_;
    const float* Bbase = qry + (long long)b * LQ_ * D_;
    float acc[4][4] = {};

    for (int k0 = 0; k0 < D_; k0 += 32) {
        #pragma unroll
        for (int it = 0; it < 2; ++it) {
            const int m  = (t >> 3) + it * 32;  // 0..63
            const int kg = t & 7;               // 0..7 -> 4 floats each
            float4 v = *(const float4*)(Abase + (long long)(c0 + m) * D_ + k0 + kg * 4);
            float4 w = *(const float4*)(wm + k0 + kg * 4);
            As[kg*4+0][m] = v.x * w.x;
            As[kg*4+1][m] = v.y * w.y;
            As[kg*4+2][m] = v.z * w.z;
            As[kg*4+3][m] = v.w * w.w;
            float4 u = *(const float4*)(Bbase + (long long)(q0 + m) * D_ + k0 + kg * 4);
            Bs[kg*4+0][m] = u.x;
            Bs[kg*4+1][m] = u.y;
            Bs[kg*4+2][m] = u.z;
            Bs[kg*4+3][m] = u.w;
        }
        __syncthreads();
        #pragma unroll
        for (int kk = 0; kk < 32; ++kk) {
            const float4 a  = *(const float4*)(&As[kk][ty * 4]);
            const float4 bb = *(const float4*)(&Bs[kk][tx * 4]);
            const float av[4] = {a.x, a.y, a.z, a.w};
            const float bv[4] = {bb.x, bb.y, bb.z, bb.w};
            #pragma unroll
            for (int i = 0; i < 4; ++i)
                #pragma unroll
                for (int j = 0; j < 4; ++j)
                    acc[i][j] = fmaf(av[i], bv[j], acc[i][j]);
        }
        __syncthreads();
    }

    const int cbase = b * LC_ + c0 + ty * 4;
    const int qbase = b * LQ_ + q0 + tx * 4;
    float scv[4], sqv[4]; int cmv[4], qmv[4];
    #pragma unroll
    for (int i = 0; i < 4; ++i) { scv[i] = sc[cbase + i]; cmv[i] = cmask[cbase + i]; }
    #pragma unroll
    for (int j = 0; j < 4; ++j) { sqv[j] = sq[qbase + j]; qmv[j] = qmask[qbase + j]; }
    float* orow = sim + (long long)cbase * LQ_ + q0 + tx * 4;
    #pragma unroll
    for (int i = 0; i < 4; ++i) {
        float4 o;
        o.x = (cmv[i] | qmv[0]) ? NEG : acc[i][0] + scv[i] + sqv[0];
        o.y = (cmv[i] | qmv[1]) ? NEG : acc[i][1] + scv[i] + sqv[1];
        o.z = (cmv[i] | qmv[2]) ? NEG : acc[i][2] + scv[i] + sqv[2];
        o.w = (cmv[i] | qmv[3]) ? NEG : acc[i][3] + scv[i] + sqv[3];
        *(float4*)(orow + (long long)i * LQ_) = o;
    }
}

// ---------------- K3: row softmax stats (over q, len 256) ----------------
__global__ __launch_bounds__(256) void k_rowstats(
    const float* __restrict__ sim, float* __restrict__ rowm, float* __restrict__ rowinvl)
{
    const int lane = threadIdx.x & 63;
    const int wave = threadIdx.x >> 6;
    const int row  = blockIdx.x * 4 + wave;  // 0 .. B_*LC_-1
    float4 v = *(const float4*)(sim + (long long)row * LQ_ + lane * 4);
    float m = fmaxf(fmaxf(v.x, v.y), fmaxf(v.z, v.w));
    #pragma unroll
    for (int off = 32; off > 0; off >>= 1) m = fmaxf(m, __shfl_xor(m, off, 64));
    float l = expf(v.x - m) + expf(v.y - m) + expf(v.z - m) + expf(v.w - m);
    #pragma unroll
    for (int off = 32; off > 0; off >>= 1) l += __shfl_xor(l, off, 64);
    if (lane == 0) { rowm[row] = m; rowinvl[row] = 1.0f / l; }
}

// ---------------- K4a: column softmax partial stats (over c, chunks of 128) ----------------
#define CCH 128
__device__ __forceinline__ void online_upd(float& m, float& l, float v) {
    float nm = fmaxf(m, v);
    l = l * expf(m - nm) + expf(v - nm);
    m = nm;
}
__global__ __launch_bounds__(256) void k_colpart(
    const float* __restrict__ sim, float* __restrict__ pm, float* __restrict__ pl)
{
    const int b  = blockIdx.x;
    const int ch = blockIdx.y;
    const int q  = threadIdx.x;
    const float* p = sim + (long long)(b * LC_ + ch * CCH) * LQ_ + q;
    float m0 = -INFINITY, l0 = 0.f, m1 = -INFINITY, l1 = 0.f;
    float m2 = -INFINITY, l2 = 0.f, m3 = -INFINITY, l3 = 0.f;
    for (int c = 0; c < CCH; c += 4) {
        float v0 = p[(long long)(c + 0) * LQ_];
        float v1 = p[(long long)(c + 1) * LQ_];
        float v2 = p[(long long)(c + 2) * LQ_];
        float v3 = p[(long long)(c + 3) * LQ_];
        online_upd(m0, l0, v0);
        online_upd(m1, l1, v1);
        online_upd(m2, l2, v2);
        online_upd(m3, l3, v3);
    }
    // merge the 4 partials
    float M = fmaxf(fmaxf(m0, m1), fmaxf(m2, m3));
    float L = l0 * expf(m0 - M) + l1 * expf(m1 - M) + l2 * expf(m2 - M) + l3 * expf(m3 - M);
    const int idx = (b * 16 + ch) * LQ_ + q;
    pm[idx] = M; pl[idx] = L;
}

// ---------------- K4b: reduce column partials ----------------
__global__ __launch_bounds__(256) void k_colreduce(
    const float* __restrict__ pm, const float* __restrict__ pl,
    float* __restrict__ colm, float* __restrict__ colinvl)
{
    const int col = blockIdx.x * 256 + threadIdx.x;  // b*LQ + q
    const int b = col >> 8, q = col & 255;
    float M = -INFINITY, L = 0.f;
    #pragma unroll
    for (int ch = 0; ch < 16; ++ch) {
        const int idx = (b * 16 + ch) * LQ_ + q;
        float m = pm[idx], l = pl[idx];
        float nM = fmaxf(M, m);
        L = L * expf(M - nM) + l * expf(m - nM);
        M = nM;
    }
    colm[col] = M; colinvl[col] = 1.0f / L;
}

// ---------------- K5/K7: out[c,d] = invl[c] * sum_q exp(sim[c,q]-m[c]) * Bsrc[q,d] ----------------
__global__ __launch_bounds__(256) void k_sgemm(
    const float* __restrict__ sim, const float* __restrict__ rowm,
    const float* __restrict__ rowinvl, const float* __restrict__ Bsrc,
    float* __restrict__ out)
{
    __shared__ __align__(16) float As[32][68];  // [q][c]  (S values)
    __shared__ __align__(16) float Bs[32][68];  // [q][d]
    const int b  = blockIdx.z;
    const int c0 = blockIdx.x * 64;
    const int d0 = blockIdx.y * 64;
    const int t  = threadIdx.x;
    const int tx = t & 15, ty = t >> 4;
    const float* Sbase = sim  + (long long)b * LC_ * LQ_;
    const float* Bbase = Bsrc + (long long)b * LQ_ * D_;
    const float* rmb = rowm + b * LC_;
    float acc[4][4] = {};

    for (int q0 = 0; q0 < LQ_; q0 += 32) {
        #pragma unroll
        for (int it = 0; it < 2; ++it) {
            const int m  = (t >> 3) + it * 32;
            const int kg = t & 7;
            float4 v = *(const float4*)(Sbase + (long long)(c0 + m) * LQ_ + q0 + kg * 4);
            const float rm = rmb[c0 + m];
            As[kg*4+0][m] = expf(v.x - rm);
            As[kg*4+1][m] = expf(v.y - rm);
            As[kg*4+2][m] = expf(v.z - rm);
            As[kg*4+3][m] = expf(v.w - rm);
            const int r  = (t >> 4) + it * 16;
            const int c4 = t & 15;
            float4 u = *(const float4*)(Bbase + (long long)(q0 + r) * D_ + d0 + c4 * 4);
            *(float4*)(&Bs[r][c4 * 4]) = u;
        }
        __syncthreads();
        #pragma unroll
        for (int kk = 0; kk < 32; ++kk) {
            const float4 a  = *(const float4*)(&As[kk][ty * 4]);
            const float4 bb = *(const float4*)(&Bs[kk][tx * 4]);
            const float av[4] = {a.x, a.y, a.z, a.w};
            const float bv[4] = {bb.x, bb.y, bb.z, bb.w};
            #pragma unroll
            for (int i = 0; i < 4; ++i)
                #pragma unroll
                for (int j = 0; j < 4; ++j)
                    acc[i][j] = fmaf(av[i], bv[j], acc[i][j]);
        }
        __syncthreads();
    }

    float il[4];
    #pragma unroll
    for (int i = 0; i < 4; ++i) il[i] = rowinvl[b * LC_ + c0 + ty * 4 + i];
    float* orow = out + (long long)(b * LC_ + c0 + ty * 4) * D_ + d0 + tx * 4;
    #pragma unroll
    for (int i = 0; i < 4; ++i) {
        float4 o;
        o.x = acc[i][0] * il[i];
        o.y = acc[i][1] * il[i];
        o.z = acc[i][2] * il[i];
        o.w = acc[i][3] * il[i];
        *(float4*)(orow + (long long)i * D_) = o;
    }
}

// ---------------- K6: T[q,d] = invl[q] * sum_c exp(sim[c,q]-m[q]) * ctx[c,d] ----------------
__global__ __launch_bounds__(256) void k_tgemm(
    const float* __restrict__ sim, const float* __restrict__ colm,
    const float* __restrict__ colinvl, const float* __restrict__ ctx,
    float* __restrict__ T)
{
    __shared__ __align__(16) float As[32][68];  // [c][q]  (SS values, pre-invl)
    __shared__ __align__(16) float Bs[32][68];  // [c][d]
    __shared__ float cm_s[64], cil_s[64];
    const int b  = blockIdx.z;
    const int q0 = blockIdx.x * 64;
    const int d0 = blockIdx.y * 64;
    const int t  = threadIdx.x;
    const int tx = t & 15, ty = t >> 4;
    if (t < 64) {
        cm_s[t]  = colm[b * LQ_ + q0 + t];
        cil_s[t] = colinvl[b * LQ_ + q0 + t];
    }
    __syncthreads();
    const float* Sbase = sim + (long long)b * LC_ * LQ_;
    const float* Cbase = ctx + (long long)b * LC_ * D_;
    float acc[4][4] = {};

    for (int c0 = 0; c0 < LC_; c0 += 32) {
        #pragma unroll
        for (int it = 0; it < 2; ++it) {
            const int r  = (t >> 4) + it * 16;  // 0..31 (c within tile)
            const int c4 = t & 15;
            float4 v = *(const float4*)(Sbase + (long long)(c0 + r) * LQ_ + q0 + c4 * 4);
            float4 e;
            e.x = expf(v.x - cm_s[c4 * 4 + 0]);
            e.y = expf(v.y - cm_s[c4 * 4 + 1]);
            e.z = expf(v.z - cm_s[c4 * 4 + 2]);
            e.w = expf(v.w - cm_s[c4 * 4 + 3]);
            *(float4*)(&As[r][c4 * 4]) = e;
            float4 u = *(const float4*)(Cbase + (long long)(c0 + r) * D_ + d0 + c4 * 4);
            *(float4*)(&Bs[r][c4 * 4]) = u;
        }
        __syncthreads();
        #pragma unroll
        for (int kk = 0; kk < 32; ++kk) {
            const float4 a  = *(const float4*)(&As[kk][ty * 4]);
            const float4 bb = *(const float4*)(&Bs[kk][tx * 4]);
            const float av[4] = {a.x, a.y, a.z, a.w};
            const float bv[4] = {bb.x, bb.y, bb.z, bb.w};
            #pragma unroll
            for (int i = 0; i < 4; ++i)
                #pragma unroll
                for (int j = 0; j < 4; ++j)
                    acc[i][j] = fmaf(av[i], bv[j], acc[i][j]);
        }
        __syncthreads();
    }

    float il[4];
    #pragma unroll
    for (int i = 0; i < 4; ++i) il[i] = cil_s[ty * 4 + i];
    float* orow = T + (long long)(b * LQ_ + q0 + ty * 4) * D_ + d0 + tx * 4;
    #pragma unroll
    for (int i = 0; i < 4; ++i) {
        float4 o;
        o.x = acc[i][0] * il[i];
        o.y = acc[i][1] * il[i];
        o.z = acc[i][2] * il[i];
        o.w = acc[i][3] * il[i];
        *(float4*)(orow + (long long)i * D_) = o;
    }
}

extern "C" void kernel_launch(void* const* d_in, const int* in_sizes, int n_in,
                              void* d_out, int out_size, void* d_ws, size_t ws_size,
                              hipStream_t stream) {
    const float* ctx   = (const float*)d_in[0];
    const float* qry   = (const float*)d_in[1];
    const int*   cmask = (const int*)d_in[2];
    const int*   qmask = (const int*)d_in[3];
    const float* w0    = (const float*)d_in[4];
    float* out = (float*)d_out;

    // workspace carve-up (floats)
    float* ws      = (float*)d_ws;
    float* sc      = ws;                    // 65536
    float* sq      = sc + 65536;            // 8192
    float* rowm    = sq + 8192;             // 65536
    float* rowinvl = rowm + 65536;          // 65536
    float* colm    = rowinvl + 65536;       // 8192
    float* colinvl = colm + 8192;           // 8192
    float* pm      = colinvl + 8192;        // 131072 (32*16*256)
    float* pl      = pm + 131072;           // 131072
    float* T       = pl + 131072;           // 2097152 (B*LQ*D)
    float* sim     = T + 2097152;           // 16777216 (B*LC*LQ)
    // total ~74 MB

    k_scsq<<<18432, 256, 0, stream>>>(ctx, qry, w0, sc, sq);
    k_sim<<<dim3(32, 4, 32), 256, 0, stream>>>(ctx, qry, cmask, qmask, w0, sc, sq, sim);
    k_rowstats<<<16384, 256, 0, stream>>>(sim, rowm, rowinvl);
    k_colpart<<<dim3(32, 16), 256, 0, stream>>>(sim, pm, pl);
    k_colreduce<<<32, 256, 0, stream>>>(pm, pl, colm, colinvl);
    k_sgemm<<<dim3(32, 4, 32), 256, 0, stream>>>(sim, rowm, rowinvl, qry, out);                       // A
    k_tgemm<<<dim3(4, 4, 32), 256, 0, stream>>>(sim, colm, colinvl, ctx, T);                          // T
    k_sgemm<<<dim3(32, 4, 32), 256, 0, stream>>>(sim, rowm, rowinvl, T, out + (long long)B_ * LC_ * D_); // Bmat
}

// Round 2
// 369.702 us; speedup vs baseline: 1.8890x; 1.8890x over previous
//
#include <hip/hip_runtime.h>

#define B_  32
#define LC_ 2048
#define LQ_ 256
#define D_  256
#define NEG (-1e30f)

typedef _Float16 f16;
typedef _Float16 f16x4 __attribute__((ext_vector_type(4)));
typedef _Float16 f16x8 __attribute__((ext_vector_type(8)));
typedef float    f32x4 __attribute__((ext_vector_type(4)));

// ---------------- K1: sc = context . wc ; sq = query . wq ----------------
__global__ __launch_bounds__(256) void k_scsq(
    const float* __restrict__ ctx, const float* __restrict__ qry,
    const float* __restrict__ w0, float* __restrict__ sc, float* __restrict__ sq)
{
    const int lane = threadIdx.x & 63;
    const int wave = threadIdx.x >> 6;
    const int row  = blockIdx.x * 4 + wave;
    const int NC = B_ * LC_;
    const int NQ = B_ * LQ_;
    const float* src; const float* w; float* dst;
    if (row < NC) { src = ctx + (long long)row * D_; w = w0; dst = sc + row; }
    else if (row < NC + NQ) { int r = row - NC; src = qry + (long long)r * D_; w = w0 + D_; dst = sq + r; }
    else return;
    float4 a = *(const float4*)(src + lane * 4);
    float4 b = *(const float4*)(w   + lane * 4);
    float v = a.x*b.x + a.y*b.y + a.z*b.z + a.w*b.w;
    #pragma unroll
    for (int off = 32; off > 0; off >>= 1) v += __shfl_down(v, off, 64);
    if (lane == 0) *dst = v;
}

// ------------- transpose+quantize: in fp32 [R][C] -> out f16 [C][R] -------------
__global__ __launch_bounds__(256) void k_transpose_q(
    const float* __restrict__ in, f16* __restrict__ out,
    int R, int C, long long in_bs, long long out_bs)
{
    __shared__ float tile[64 * 65];
    const int b = blockIdx.z;
    const int r0 = blockIdx.x * 64, c0 = blockIdx.y * 64;
    const int t = threadIdx.x;
    const float* ib = in + (long long)b * in_bs;
    #pragma unroll
    for (int p = 0; p < 4; ++p) {
        int r = (t >> 4) + p * 16;
        int cb = (t & 15) * 4;
        float4 v = *(const float4*)(ib + (long long)(r0 + r) * C + c0 + cb);
        tile[r * 65 + cb + 0] = v.x;
        tile[r * 65 + cb + 1] = v.y;
        tile[r * 65 + cb + 2] = v.z;
        tile[r * 65 + cb + 3] = v.w;
    }
    __syncthreads();
    f16* ob = out + (long long)b * out_bs;
    #pragma unroll
    for (int p = 0; p < 4; ++p) {
        int c = (t >> 4) + p * 16;
        int rb = (t & 15) * 4;
        f16x4 h;
        h[0] = (f16)tile[(rb + 0) * 65 + c];
        h[1] = (f16)tile[(rb + 1) * 65 + c];
        h[2] = (f16)tile[(rb + 2) * 65 + c];
        h[3] = (f16)tile[(rb + 3) * 65 + c];
        *(f16x4*)(ob + (long long)(c0 + c) * R + r0 + rb) = h;
    }
}

// ---------------- G1: sim[c][q] MFMA GEMM + sc/sq + mask ----------------
#define LDA1 40   // padded f16 row stride for BK=32 tiles (80B: 16B-aligned, 2-way max)
__global__ __launch_bounds__(256) void k_g1(
    const float* __restrict__ ctx, const float* __restrict__ qry,
    const float* __restrict__ w0, const float* __restrict__ sc,
    const float* __restrict__ sq, const int* __restrict__ cmask,
    const int* __restrict__ qmask, float* __restrict__ sim)
{
    __shared__ f16 As[128 * LDA1];
    __shared__ f16 Bs[128 * LDA1];
    const int b = blockIdx.z;
    const int c0 = blockIdx.x * 128, q0 = blockIdx.y * 128;
    const int t = threadIdx.x, lane = t & 63, wv = t >> 6;
    const int wm_off = (wv >> 1) * 64, wn_off = (wv & 1) * 64;
    const float* Ab = ctx + (long long)b * LC_ * D_;
    const float* Bb = qry + (long long)b * LQ_ * D_;
    const float* wmp = w0 + 2 * D_;
    const int srow = t >> 3, scg = (t & 7) * 4;
    f32x4 acc[4][4] = {};
    for (int k0 = 0; k0 < D_; k0 += 32) {
        float4 wm4 = *(const float4*)(wmp + k0 + scg);
        #pragma unroll
        for (int p = 0; p < 4; ++p) {
            int r = srow + p * 32;
            float4 v = *(const float4*)(Ab + (long long)(c0 + r) * D_ + k0 + scg);
            f16x4 h;
            h[0] = (f16)(v.x * wm4.x); h[1] = (f16)(v.y * wm4.y);
            h[2] = (f16)(v.z * wm4.z); h[3] = (f16)(v.w * wm4.w);
            *(f16x4*)(As + r * LDA1 + scg) = h;
            float4 u = *(const float4*)(Bb + (long long)(q0 + r) * D_ + k0 + scg);
            f16x4 g;
            g[0] = (f16)u.x; g[1] = (f16)u.y; g[2] = (f16)u.z; g[3] = (f16)u.w;
            *(f16x4*)(Bs + r * LDA1 + scg) = g;
        }
        __syncthreads();
        f16x8 af[4], bf[4];
        #pragma unroll
        for (int i = 0; i < 4; ++i)
            af[i] = *(const f16x8*)(As + (wm_off + i * 16 + (lane & 15)) * LDA1 + (lane >> 4) * 8);
        #pragma unroll
        for (int j = 0; j < 4; ++j)
            bf[j] = *(const f16x8*)(Bs + (wn_off + j * 16 + (lane & 15)) * LDA1 + (lane >> 4) * 8);
        #pragma unroll
        for (int i = 0; i < 4; ++i)
            #pragma unroll
            for (int j = 0; j < 4; ++j)
                acc[i][j] = __builtin_amdgcn_mfma_f32_16x16x32_f16(af[i], bf[j], acc[i][j], 0, 0, 0);
        __syncthreads();
    }
    float sqv[4]; int qmv[4];
    #pragma unroll
    for (int j = 0; j < 4; ++j) {
        int q = q0 + wn_off + j * 16 + (lane & 15);
        sqv[j] = sq[b * LQ_ + q];
        qmv[j] = qmask[b * LQ_ + q];
    }
    #pragma unroll
    for (int i = 0; i < 4; ++i) {
        #pragma unroll
        for (int r = 0; r < 4; ++r) {
            int c = c0 + wm_off + i * 16 + (lane >> 4) * 4 + r;
            float scv = sc[b * LC_ + c];
            int cm = cmask[b * LC_ + c];
            float* orow = sim + ((long long)b * LC_ + c) * LQ_ + q0 + wn_off + (lane & 15);
            #pragma unroll
            for (int j = 0; j < 4; ++j) {
                float val = acc[i][j][r] + scv + sqv[j];
                orow[j * 16] = (cm | qmv[j]) ? NEG : val;
            }
        }
    }
}

// ---------------- S1: one pass over sim -> row stats + column partials ----------------
__global__ __launch_bounds__(256) void k_s1(
    const float* __restrict__ sim, float* __restrict__ rowm, float* __restrict__ rowinvl,
    float* __restrict__ pm, float* __restrict__ pl)
{
    __shared__ float tile[32 * 260];
    const int ch = blockIdx.x;  // 0..63 -> 32 rows each
    const int b  = blockIdx.y;
    const int t  = threadIdx.x;
    const int c0 = ch * 32;
    const float* sb = sim + ((long long)b * LC_ + c0) * LQ_;
    #pragma unroll
    for (int p = 0; p < 8; ++p) {
        int r = p * 4 + (t >> 6);
        int cb = (t & 63) * 4;
        float4 v = *(const float4*)(sb + (long long)r * LQ_ + cb);
        *(float4*)(tile + r * 260 + cb) = v;
    }
    __syncthreads();
    // row stats: 8 threads per row, interleaved columns (bank-friendly)
    {
        int r = t >> 3, s = t & 7;
        const float* rp = tile + r * 260;
        float m = -INFINITY;
        #pragma unroll
        for (int i = 0; i < 32; ++i) m = fmaxf(m, rp[(i << 3) + s]);
        m = fmaxf(m, __shfl_xor(m, 1, 64));
        m = fmaxf(m, __shfl_xor(m, 2, 64));
        m = fmaxf(m, __shfl_xor(m, 4, 64));
        float l = 0.f;
        #pragma unroll
        for (int i = 0; i < 32; ++i) l += __expf(rp[(i << 3) + s] - m);
        l += __shfl_xor(l, 1, 64);
        l += __shfl_xor(l, 2, 64);
        l += __shfl_xor(l, 4, 64);
        if (s == 0) {
            rowm[b * LC_ + c0 + r] = m;
            rowinvl[b * LC_ + c0 + r] = 1.0f / l;
        }
    }
    // column partials: thread t -> column q = t
    {
        float m = -INFINITY;
        #pragma unroll 8
        for (int r = 0; r < 32; ++r) m = fmaxf(m, tile[r * 260 + t]);
        float l = 0.f;
        #pragma unroll 8
        for (int r = 0; r < 32; ++r) l += __expf(tile[r * 260 + t] - m);
        int idx = (b * 64 + ch) * LQ_ + t;
        pm[idx] = m; pl[idx] = l;
    }
}

// ---------------- reduce column partials ----------------
__global__ __launch_bounds__(256) void k_colreduce(
    const float* __restrict__ pm, const float* __restrict__ pl,
    float* __restrict__ colm, float* __restrict__ colinvl)
{
    const int col = blockIdx.x * 256 + threadIdx.x;  // b*LQ + q
    const int b = col >> 8, q = col & 255;
    float M = -INFINITY, L = 0.f;
    for (int ch = 0; ch < 64; ++ch) {
        int idx = (b * 64 + ch) * LQ_ + q;
        float m = pm[idx], l = pl[idx];
        float nM = fmaxf(M, m);
        L = L * __expf(M - nM) + l * __expf(m - nM);
        M = nM;
    }
    colm[col] = M; colinvl[col] = 1.0f / L;
}

// ---------------- S2: E[q][c] = f16(exp(sim[c][q] - colm[q])) (transposed) ----------------
__global__ __launch_bounds__(256) void k_s2(
    const float* __restrict__ sim, const float* __restrict__ colm,
    f16* __restrict__ E)
{
    __shared__ float tile[64 * 65];
    const int c0 = blockIdx.x * 64, q0 = blockIdx.y * 64, b = blockIdx.z;
    const int t = threadIdx.x;
    const float* sb = sim + ((long long)b * LC_ + c0) * LQ_ + q0;
    #pragma unroll
    for (int p = 0; p < 4; ++p) {
        int r = (t >> 4) + p * 16;
        int cb = (t & 15) * 4;
        float4 v = *(const float4*)(sb + (long long)r * LQ_ + cb);
        tile[r * 65 + cb + 0] = v.x;
        tile[r * 65 + cb + 1] = v.y;
        tile[r * 65 + cb + 2] = v.z;
        tile[r * 65 + cb + 3] = v.w;
    }
    __syncthreads();
    #pragma unroll
    for (int p = 0; p < 4; ++p) {
        int ql = (t >> 4) + p * 16;
        int cb = (t & 15) * 4;
        float cm = colm[b * LQ_ + q0 + ql];
        f16x4 h;
        h[0] = (f16)__expf(tile[(cb + 0) * 65 + ql] - cm);
        h[1] = (f16)__expf(tile[(cb + 1) * 65 + ql] - cm);
        h[2] = (f16)__expf(tile[(cb + 2) * 65 + ql] - cm);
        h[3] = (f16)__expf(tile[(cb + 3) * 65 + ql] - cm);
        *(f16x4*)(E + ((long long)b * LQ_ + q0 + ql) * LC_ + c0 + cb) = h;
    }
}

// ---------------- G3: Tt[d][q] = colinvl[q] * sum_c ctxt[d][c]*E[q][c] -> Bcat[256+d][q] f16 ----------------
#define LDA3 72   // padded f16 row stride for BK=64 tiles
__global__ __launch_bounds__(256) void k_g3(
    const f16* __restrict__ ctxt, const f16* __restrict__ E,
    const float* __restrict__ colinvl, f16* __restrict__ Bcat)
{
    __shared__ f16 As[64 * LDA3];
    __shared__ f16 Bs[64 * LDA3];
    const int d0 = blockIdx.x * 64, q0 = blockIdx.y * 64, b = blockIdx.z;
    const int t = threadIdx.x, lane = t & 63, wv = t >> 6;
    const int wm_off = (wv >> 1) * 32, wn_off = (wv & 1) * 32;
    const f16* Ab = ctxt + (long long)b * D_ * LC_;
    const f16* Bb = E + (long long)b * LQ_ * LC_;
    const int srow = t >> 3, sch = (t & 7) * 8;
    f32x4 acc[2][2] = {};
    for (int k0 = 0; k0 < LC_; k0 += 64) {
        #pragma unroll
        for (int p = 0; p < 2; ++p) {
            int r = srow + p * 32;
            *(uint4*)(As + r * LDA3 + sch) = *(const uint4*)(Ab + (long long)(d0 + r) * LC_ + k0 + sch);
            *(uint4*)(Bs + r * LDA3 + sch) = *(const uint4*)(Bb + (long long)(q0 + r) * LC_ + k0 + sch);
        }
        __syncthreads();
        #pragma unroll
        for (int kk = 0; kk < 64; kk += 32) {
            f16x8 af[2], bf[2];
            #pragma unroll
            for (int i = 0; i < 2; ++i)
                af[i] = *(const f16x8*)(As + (wm_off + i * 16 + (lane & 15)) * LDA3 + kk + (lane >> 4) * 8);
            #pragma unroll
            for (int j = 0; j < 2; ++j)
                bf[j] = *(const f16x8*)(Bs + (wn_off + j * 16 + (lane & 15)) * LDA3 + kk + (lane >> 4) * 8);
            #pragma unroll
            for (int i = 0; i < 2; ++i)
                #pragma unroll
                for (int j = 0; j < 2; ++j)
                    acc[i][j] = __builtin_amdgcn_mfma_f32_16x16x32_f16(af[i], bf[j], acc[i][j], 0, 0, 0);
        }
        __syncthreads();
    }
    float cinv[2];
    #pragma unroll
    for (int j = 0; j < 2; ++j)
        cinv[j] = colinvl[b * LQ_ + q0 + wn_off + j * 16 + (lane & 15)];
    #pragma unroll
    for (int i = 0; i < 2; ++i) {
        #pragma unroll
        for (int r = 0; r < 4; ++r) {
            int d = d0 + wm_off + i * 16 + (lane >> 4) * 4 + r;
            f16* orow = Bcat + (long long)b * 512 * LQ_ + (long long)(256 + d) * LQ_ + q0 + wn_off + (lane & 15);
            #pragma unroll
            for (int j = 0; j < 2; ++j)
                orow[j * 16] = (f16)(acc[i][j][r] * cinv[j]);
        }
    }
}

// ---------------- G23: [A | Bmat] = rowinvl * exp(sim - rowm) @ Bcat^T ----------------
__global__ __launch_bounds__(256) void k_g23(
    const float* __restrict__ sim, const float* __restrict__ rowm,
    const float* __restrict__ rowinvl, const f16* __restrict__ Bcat,
    float* __restrict__ outA, float* __restrict__ outB)
{
    __shared__ f16 As[128 * LDA1];
    __shared__ f16 Bs[128 * LDA1];
    const int b = blockIdx.z;
    const int c0 = blockIdx.x * 128, n0 = blockIdx.y * 128;
    const int t = threadIdx.x, lane = t & 63, wv = t >> 6;
    const int wm_off = (wv >> 1) * 64, wn_off = (wv & 1) * 64;
    const float* Ab = sim + ((long long)b * LC_ + c0) * LQ_;
    const f16* Bb = Bcat + (long long)b * 512 * LQ_ + (long long)n0 * LQ_;
    const int srow = t >> 3, scg = (t & 7) * 4;
    const int brow = t >> 2, bch = (t & 3) * 8;
    float rm[4];
    #pragma unroll
    for (int p = 0; p < 4; ++p) rm[p] = rowm[b * LC_ + c0 + srow + p * 32];
    f32x4 acc[4][4] = {};
    for (int k0 = 0; k0 < LQ_; k0 += 32) {
        #pragma unroll
        for (int p = 0; p < 4; ++p) {
            int r = srow + p * 32;
            float4 v = *(const float4*)(Ab + (long long)r * LQ_ + k0 + scg);
            f16x4 h;
            h[0] = (f16)__expf(v.x - rm[p]);
            h[1] = (f16)__expf(v.y - rm[p]);
            h[2] = (f16)__expf(v.z - rm[p]);
            h[3] = (f16)__expf(v.w - rm[p]);
            *(f16x4*)(As + r * LDA1 + scg) = h;
        }
        #pragma unroll
        for (int p = 0; p < 2; ++p) {
            int r = brow + p * 64;
            *(uint4*)(Bs + r * LDA1 + bch) = *(const uint4*)(Bb + (long long)r * LQ_ + k0 + bch);
        }
        __syncthreads();
        f16x8 af[4], bf[4];
        #pragma unroll
        for (int i = 0; i < 4; ++i)
            af[i] = *(const f16x8*)(As + (wm_off + i * 16 + (lane & 15)) * LDA1 + (lane >> 4) * 8);
        #pragma unroll
        for (int j = 0; j < 4; ++j)
            bf[j] = *(const f16x8*)(Bs + (wn_off + j * 16 + (lane & 15)) * LDA1 + (lane >> 4) * 8);
        #pragma unroll
        for (int i = 0; i < 4; ++i)
            #pragma unroll
            for (int j = 0; j < 4; ++j)
                acc[i][j] = __builtin_amdgcn_mfma_f32_16x16x32_f16(af[i], bf[j], acc[i][j], 0, 0, 0);
        __syncthreads();
    }
    float* outp = (n0 < 256) ? outA : outB;
    const int nbase = (n0 < 256) ? n0 : (n0 - 256);
    #pragma unroll
    for (int i = 0; i < 4; ++i) {
        #pragma unroll
        for (int r = 0; r < 4; ++r) {
            int c = c0 + wm_off + i * 16 + (lane >> 4) * 4 + r;
            float ri = rowinvl[b * LC_ + c];
            float* orow = outp + ((long long)b * LC_ + c) * D_ + nbase + wn_off + (lane & 15);
            #pragma unroll
            for (int j = 0; j < 4; ++j)
                orow[j * 16] = acc[i][j][r] * ri;
        }
    }
}

extern "C" void kernel_launch(void* const* d_in, const int* in_sizes, int n_in,
                              void* d_out, int out_size, void* d_ws, size_t ws_size,
                              hipStream_t stream) {
    const float* ctx   = (const float*)d_in[0];
    const float* qry   = (const float*)d_in[1];
    const int*   cmask = (const int*)d_in[2];
    const int*   qmask = (const int*)d_in[3];
    const float* w0    = (const float*)d_in[4];
    float* out = (float*)d_out;

    char* w = (char*)d_ws;
    float* sc      = (float*)w;  w += (long long)65536 * 4;
    float* sq      = (float*)w;  w += (long long)8192 * 4;
    float* rowm    = (float*)w;  w += (long long)65536 * 4;
    float* rowinvl = (float*)w;  w += (long long)65536 * 4;
    float* colm    = (float*)w;  w += (long long)8192 * 4;
    float* colinvl = (float*)w;  w += (long long)8192 * 4;
    float* pm      = (float*)w;  w += (long long)524288 * 4;
    float* pl      = (float*)w;  w += (long long)524288 * 4;
    float* sim     = (float*)w;  w += (long long)16777216 * 4;
    f16*   ctxt    = (f16*)w;    w += (long long)16777216 * 2;
    f16*   E       = (f16*)w;    w += (long long)16777216 * 2;
    f16*   Bcat    = (f16*)w;    w += (long long)4194304 * 2;

    k_scsq<<<18432, 256, 0, stream>>>(ctx, qry, w0, sc, sq);
    k_transpose_q<<<dim3(32, 4, 32), 256, 0, stream>>>(ctx, ctxt, LC_, D_,
        (long long)LC_ * D_, (long long)D_ * LC_);
    k_transpose_q<<<dim3(4, 4, 32), 256, 0, stream>>>(qry, Bcat, LQ_, D_,
        (long long)LQ_ * D_, (long long)512 * LQ_);
    k_g1<<<dim3(16, 2, 32), 256, 0, stream>>>(ctx, qry, w0, sc, sq, cmask, qmask, sim);
    k_s1<<<dim3(64, 32), 256, 0, stream>>>(sim, rowm, rowinvl, pm, pl);
    k_colreduce<<<32, 256, 0, stream>>>(pm, pl, colm, colinvl);
    k_s2<<<dim3(32, 4, 32), 256, 0, stream>>>(sim, colm, E);
    k_g3<<<dim3(4, 4, 32), 256, 0, stream>>>(ctxt, E, colinvl, Bcat);
    k_g23<<<dim3(16, 4, 32), 256, 0, stream>>>(sim, rowm, rowinvl, Bcat,
        out, out + (long long)B_ * LC_ * D_);
}

// Round 3
// 327.325 us; speedup vs baseline: 2.1336x; 1.1295x over previous
//
#include <hip/hip_runtime.h>

#define B_  32
#define LC_ 2048
#define LQ_ 256
#define D_  256
#define NEGH (-30000.0f)   // f16-safe mask value

typedef _Float16 f16;
typedef _Float16 f16x4 __attribute__((ext_vector_type(4)));
typedef _Float16 f16x8 __attribute__((ext_vector_type(8)));
typedef float    f32x4 __attribute__((ext_vector_type(4)));

// ---- K1: cast ctx->f16, qry->qry*wm f16; sc = ctx.wc, sq = qry.wq ----
__global__ __launch_bounds__(256) void k_prep(
    const float* __restrict__ ctx, const float* __restrict__ qry,
    const float* __restrict__ w0, f16* __restrict__ ctx16,
    f16* __restrict__ qrywm16, float* __restrict__ sc, float* __restrict__ sq)
{
    const int lane = threadIdx.x & 63;
    const int wave = threadIdx.x >> 6;
    const int row  = blockIdx.x * 4 + wave;
    const int NC = B_ * LC_;
    if (row < NC) {
        float4 v = *(const float4*)(ctx + (long long)row * D_ + lane * 4);
        f16x4 h; h[0] = (f16)v.x; h[1] = (f16)v.y; h[2] = (f16)v.z; h[3] = (f16)v.w;
        *(f16x4*)(ctx16 + (long long)row * D_ + lane * 4) = h;
        float4 wc = *(const float4*)(w0 + lane * 4);
        float s = v.x*wc.x + v.y*wc.y + v.z*wc.z + v.w*wc.w;
        #pragma unroll
        for (int off = 32; off > 0; off >>= 1) s += __shfl_down(s, off, 64);
        if (lane == 0) sc[row] = s;
    } else {
        int r = row - NC;
        float4 v = *(const float4*)(qry + (long long)r * D_ + lane * 4);
        float4 wm = *(const float4*)(w0 + 2 * D_ + lane * 4);
        f16x4 h;
        h[0] = (f16)(v.x * wm.x); h[1] = (f16)(v.y * wm.y);
        h[2] = (f16)(v.z * wm.z); h[3] = (f16)(v.w * wm.w);
        *(f16x4*)(qrywm16 + (long long)r * D_ + lane * 4) = h;
        float4 wq = *(const float4*)(w0 + D_ + lane * 4);
        float s = v.x*wq.x + v.y*wq.y + v.z*wq.z + v.w*wq.w;
        #pragma unroll
        for (int off = 32; off > 0; off >>= 1) s += __shfl_down(s, off, 64);
        if (lane == 0) sq[r] = s;
    }
}

// ---- K2: transpose qry fp32 [q][d] -> f16 Bcat[0:256] rows [d][q] ----
__global__ __launch_bounds__(256) void k_tq(
    const float* __restrict__ in, f16* __restrict__ out)
{
    __shared__ float tile[64 * 65];
    const int b = blockIdx.z;
    const int r0 = blockIdx.x * 64, c0 = blockIdx.y * 64;
    const int t = threadIdx.x;
    const float* ib = in + (long long)b * LQ_ * D_;
    #pragma unroll
    for (int p = 0; p < 4; ++p) {
        int r = (t >> 4) + p * 16;
        int cb = (t & 15) * 4;
        float4 v = *(const float4*)(ib + (long long)(r0 + r) * D_ + c0 + cb);
        tile[r * 65 + cb + 0] = v.x;
        tile[r * 65 + cb + 1] = v.y;
        tile[r * 65 + cb + 2] = v.z;
        tile[r * 65 + cb + 3] = v.w;
    }
    __syncthreads();
    f16* ob = out + (long long)b * 512 * LQ_;
    #pragma unroll
    for (int p = 0; p < 4; ++p) {
        int c = (t >> 4) + p * 16;
        int rb = (t & 15) * 4;
        f16x4 h;
        h[0] = (f16)tile[(rb + 0) * 65 + c];
        h[1] = (f16)tile[(rb + 1) * 65 + c];
        h[2] = (f16)tile[(rb + 2) * 65 + c];
        h[3] = (f16)tile[(rb + 3) * 65 + c];
        *(f16x4*)(ob + (long long)(c0 + c) * LQ_ + r0 + rb) = h;
    }
}

// ---- G1: sim16[c][q] = f16(ctx16 @ qrywm16^T + sc + sq, masked) ----
// block: 128c x 256q (full LQ), each ctx16 byte read exactly once
#define LDA1 40
__global__ __launch_bounds__(256) void k_g1(
    const f16* __restrict__ ctx16, const f16* __restrict__ qrywm16,
    const float* __restrict__ sc, const float* __restrict__ sq,
    const int* __restrict__ cmask, const int* __restrict__ qmask,
    f16* __restrict__ sim16)
{
    __shared__ f16 As[128 * LDA1];
    __shared__ f16 Bs[256 * LDA1];
    const int b = blockIdx.z;
    const int c0 = blockIdx.x * 128;
    const int t = threadIdx.x, lane = t & 63, wv = t >> 6;
    const int wm_off = (wv >> 1) * 64, wn_off = (wv & 1) * 128;
    const f16* Ab = ctx16 + ((long long)b * LC_ + c0) * D_;
    const f16* Bb = qrywm16 + (long long)b * LQ_ * D_;
    const int srow = t >> 2, scg = (t & 3) * 8;
    f32x4 acc[4][8] = {};
    for (int k0 = 0; k0 < D_; k0 += 32) {
        #pragma unroll
        for (int p = 0; p < 2; ++p) {
            int r = srow + p * 64;
            *(f16x8*)(As + r * LDA1 + scg) = *(const f16x8*)(Ab + (long long)r * D_ + k0 + scg);
        }
        #pragma unroll
        for (int p = 0; p < 4; ++p) {
            int r = srow + p * 64;
            *(f16x8*)(Bs + r * LDA1 + scg) = *(const f16x8*)(Bb + (long long)r * D_ + k0 + scg);
        }
        __syncthreads();
        f16x8 af[4], bf[8];
        #pragma unroll
        for (int i = 0; i < 4; ++i)
            af[i] = *(const f16x8*)(As + (wm_off + i * 16 + (lane & 15)) * LDA1 + (lane >> 4) * 8);
        #pragma unroll
        for (int j = 0; j < 8; ++j)
            bf[j] = *(const f16x8*)(Bs + (wn_off + j * 16 + (lane & 15)) * LDA1 + (lane >> 4) * 8);
        #pragma unroll
        for (int i = 0; i < 4; ++i)
            #pragma unroll
            for (int j = 0; j < 8; ++j)
                acc[i][j] = __builtin_amdgcn_mfma_f32_16x16x32_f16(af[i], bf[j], acc[i][j], 0, 0, 0);
        __syncthreads();
    }
    float sqv[8]; int qmv[8];
    #pragma unroll
    for (int j = 0; j < 8; ++j) {
        int q = wn_off + j * 16 + (lane & 15);
        sqv[j] = sq[b * LQ_ + q];
        qmv[j] = qmask[b * LQ_ + q];
    }
    #pragma unroll
    for (int i = 0; i < 4; ++i) {
        #pragma unroll
        for (int r = 0; r < 4; ++r) {
            int c = c0 + wm_off + i * 16 + (lane >> 4) * 4 + r;
            float scv = sc[b * LC_ + c];
            int cm = cmask[b * LC_ + c];
            f16* orow = sim16 + ((long long)b * LC_ + c) * LQ_ + wn_off + (lane & 15);
            #pragma unroll
            for (int j = 0; j < 8; ++j) {
                float val = (cm | qmv[j]) ? NEGH : (acc[i][j][r] + scv + sqv[j]);
                orow[j * 16] = (f16)val;
            }
        }
    }
}

// ---- S1: one pass over sim16 -> row stats + column partials ----
__global__ __launch_bounds__(256) void k_s1(
    const f16* __restrict__ sim16, float* __restrict__ rowm, float* __restrict__ rowinvl,
    float* __restrict__ pm, float* __restrict__ pl)
{
    __shared__ float tile[32 * 260];
    const int ch = blockIdx.x;  // 64 chunks of 32 rows
    const int b  = blockIdx.y;
    const int t  = threadIdx.x;
    const int c0 = ch * 32;
    const f16* sb = sim16 + ((long long)b * LC_ + c0) * LQ_;
    #pragma unroll
    for (int p = 0; p < 8; ++p) {
        int r = p * 4 + (t >> 6);
        int cb = (t & 63) * 4;
        f16x4 v = *(const f16x4*)(sb + (long long)r * LQ_ + cb);
        tile[r * 260 + cb + 0] = (float)v[0];
        tile[r * 260 + cb + 1] = (float)v[1];
        tile[r * 260 + cb + 2] = (float)v[2];
        tile[r * 260 + cb + 3] = (float)v[3];
    }
    __syncthreads();
    {
        int r = t >> 3, s = t & 7;
        const float* rp = tile + r * 260;
        float m = -INFINITY;
        #pragma unroll
        for (int i = 0; i < 32; ++i) m = fmaxf(m, rp[(i << 3) + s]);
        m = fmaxf(m, __shfl_xor(m, 1, 64));
        m = fmaxf(m, __shfl_xor(m, 2, 64));
        m = fmaxf(m, __shfl_xor(m, 4, 64));
        float l = 0.f;
        #pragma unroll
        for (int i = 0; i < 32; ++i) l += __expf(rp[(i << 3) + s] - m);
        l += __shfl_xor(l, 1, 64);
        l += __shfl_xor(l, 2, 64);
        l += __shfl_xor(l, 4, 64);
        if (s == 0) {
            rowm[b * LC_ + c0 + r] = m;
            rowinvl[b * LC_ + c0 + r] = 1.0f / l;
        }
    }
    {
        float m = -INFINITY;
        #pragma unroll 8
        for (int r = 0; r < 32; ++r) m = fmaxf(m, tile[r * 260 + t]);
        float l = 0.f;
        #pragma unroll 8
        for (int r = 0; r < 32; ++r) l += __expf(tile[r * 260 + t] - m);
        int idx = (b * 64 + ch) * LQ_ + t;
        pm[idx] = m; pl[idx] = l;
    }
}

__global__ __launch_bounds__(256) void k_colreduce(
    const float* __restrict__ pm, const float* __restrict__ pl,
    float* __restrict__ colm, float* __restrict__ colinvl)
{
    const int col = blockIdx.x * 256 + threadIdx.x;
    const int b = col >> 8, q = col & 255;
    float M = -INFINITY, L = 0.f;
    for (int ch = 0; ch < 64; ++ch) {
        int idx = (b * 64 + ch) * LQ_ + q;
        float m = pm[idx], l = pl[idx];
        float nM = fmaxf(M, m);
        L = L * __expf(M - nM) + l * __expf(m - nM);
        M = nM;
    }
    colm[col] = M; colinvl[col] = 1.0f / L;
}

// ---- G3: Tt[d][q] = colinvl[q] * sum_c ctx[c][d]*exp(sim[c][q]-colm[q]) ----
// -> Bcat[256+d][q] f16.  Both operands LDS-transposed at staging.
#define LDA3 66
__global__ __launch_bounds__(256) void k_g3(
    const f16* __restrict__ ctx16, const f16* __restrict__ sim16,
    const float* __restrict__ colm, const float* __restrict__ colinvl,
    f16* __restrict__ Bcat)
{
    __shared__ f16 As[128 * LDA3];   // [d][c]
    __shared__ f16 Bs[64 * LDA3];    // [q][c]
    __shared__ float colm_s[64], cil_s[64];
    const int b = blockIdx.x;
    const int combo = blockIdx.y;          // qt(0..3) + 4*dh(0..1)
    const int qt = combo & 3, dh = combo >> 2;
    const int q0 = qt * 64, d0 = dh * 128;
    const int t = threadIdx.x, lane = t & 63, wv = t >> 6;
    const int wm_off = (wv >> 1) * 64, wn_off = (wv & 1) * 32;
    if (t < 64) {
        colm_s[t] = colm[b * LQ_ + q0 + t];
        cil_s[t]  = colinvl[b * LQ_ + q0 + t];
    }
    __syncthreads();
    const f16* Ab = ctx16 + (long long)b * LC_ * D_;
    const f16* Sb = sim16 + (long long)b * LC_ * LQ_;
    f32x4 acc[4][2] = {};
    const int acc_ = t >> 4, ad8 = (t & 15) * 8;   // A staging: c-row, d-col8
    const int bcc = t >> 3, bq8 = (t & 7) * 8;     // B staging: c-row, q-col8
    for (int c0 = 0; c0 < LC_; c0 += 64) {
        #pragma unroll
        for (int p = 0; p < 4; ++p) {
            int cc = acc_ + p * 16;
            f16x8 h = *(const f16x8*)(Ab + (long long)(c0 + cc) * D_ + d0 + ad8);
            #pragma unroll
            for (int j = 0; j < 8; ++j)
                As[(ad8 + j) * LDA3 + cc] = h[j];
        }
        #pragma unroll
        for (int p = 0; p < 2; ++p) {
            int cc = bcc + p * 32;
            f16x8 h = *(const f16x8*)(Sb + (long long)(c0 + cc) * LQ_ + q0 + bq8);
            #pragma unroll
            for (int j = 0; j < 8; ++j)
                Bs[(bq8 + j) * LDA3 + cc] = (f16)__expf((float)h[j] - colm_s[bq8 + j]);
        }
        __syncthreads();
        #pragma unroll
        for (int kk = 0; kk < 64; kk += 32) {
            f16x8 af[4], bf[2];
            #pragma unroll
            for (int i = 0; i < 4; ++i)
                af[i] = *(const f16x8*)(As + (wm_off + i * 16 + (lane & 15)) * LDA3 + kk + (lane >> 4) * 8);
            #pragma unroll
            for (int j = 0; j < 2; ++j)
                bf[j] = *(const f16x8*)(Bs + (wn_off + j * 16 + (lane & 15)) * LDA3 + kk + (lane >> 4) * 8);
            #pragma unroll
            for (int i = 0; i < 4; ++i)
                #pragma unroll
                for (int j = 0; j < 2; ++j)
                    acc[i][j] = __builtin_amdgcn_mfma_f32_16x16x32_f16(af[i], bf[j], acc[i][j], 0, 0, 0);
        }
        __syncthreads();
    }
    #pragma unroll
    for (int i = 0; i < 4; ++i) {
        #pragma unroll
        for (int r = 0; r < 4; ++r) {
            int d = d0 + wm_off + i * 16 + (lane >> 4) * 4 + r;
            f16* orow = Bcat + (long long)b * 512 * LQ_ + (long long)(256 + d) * LQ_ + q0 + wn_off + (lane & 15);
            #pragma unroll
            for (int j = 0; j < 2; ++j)
                orow[j * 16] = (f16)(acc[i][j][r] * cil_s[wn_off + j * 16 + (lane & 15)]);
        }
    }
}

// ---- G23: [A | Bmat] = rowinvl * exp(sim16 - rowm) @ Bcat^T ----
__global__ __launch_bounds__(256) void k_g23(
    const f16* __restrict__ sim16, const float* __restrict__ rowm,
    const float* __restrict__ rowinvl, const f16* __restrict__ Bcat,
    float* __restrict__ outA, float* __restrict__ outB)
{
    __shared__ f16 As[128 * LDA1];
    __shared__ f16 Bs[128 * LDA1];
    const int b = blockIdx.z;
    const int c0 = blockIdx.x * 128, n0 = blockIdx.y * 128;
    const int t = threadIdx.x, lane = t & 63, wv = t >> 6;
    const int wm_off = (wv >> 1) * 64, wn_off = (wv & 1) * 64;
    const f16* Ab = sim16 + ((long long)b * LC_ + c0) * LQ_;
    const f16* Bb = Bcat + ((long long)b * 512 + n0) * LQ_;
    const int srow = t >> 2, scg = (t & 3) * 8;
    float rm[2];
    #pragma unroll
    for (int p = 0; p < 2; ++p) rm[p] = rowm[b * LC_ + c0 + srow + p * 64];
    f32x4 acc[4][4] = {};
    for (int k0 = 0; k0 < LQ_; k0 += 32) {
        #pragma unroll
        for (int p = 0; p < 2; ++p) {
            int r = srow + p * 64;
            f16x8 h = *(const f16x8*)(Ab + (long long)r * LQ_ + k0 + scg);
            f16x8 e;
            #pragma unroll
            for (int j = 0; j < 8; ++j) e[j] = (f16)__expf((float)h[j] - rm[p]);
            *(f16x8*)(As + r * LDA1 + scg) = e;
            *(f16x8*)(Bs + r * LDA1 + scg) = *(const f16x8*)(Bb + (long long)r * LQ_ + k0 + scg);
        }
        __syncthreads();
        f16x8 af[4], bf[4];
        #pragma unroll
        for (int i = 0; i < 4; ++i)
            af[i] = *(const f16x8*)(As + (wm_off + i * 16 + (lane & 15)) * LDA1 + (lane >> 4) * 8);
        #pragma unroll
        for (int j = 0; j < 4; ++j)
            bf[j] = *(const f16x8*)(Bs + (wn_off + j * 16 + (lane & 15)) * LDA1 + (lane >> 4) * 8);
        #pragma unroll
        for (int i = 0; i < 4; ++i)
            #pragma unroll
            for (int j = 0; j < 4; ++j)
                acc[i][j] = __builtin_amdgcn_mfma_f32_16x16x32_f16(af[i], bf[j], acc[i][j], 0, 0, 0);
        __syncthreads();
    }
    float* outp = (n0 < 256) ? outA : outB;
    const int nbase = (n0 < 256) ? n0 : (n0 - 256);
    #pragma unroll
    for (int i = 0; i < 4; ++i) {
        #pragma unroll
        for (int r = 0; r < 4; ++r) {
            int c = c0 + wm_off + i * 16 + (lane >> 4) * 4 + r;
            float ri = rowinvl[b * LC_ + c];
            float* orow = outp + ((long long)b * LC_ + c) * D_ + nbase + wn_off + (lane & 15);
            #pragma unroll
            for (int j = 0; j < 4; ++j)
                orow[j * 16] = acc[i][j][r] * ri;
        }
    }
}

extern "C" void kernel_launch(void* const* d_in, const int* in_sizes, int n_in,
                              void* d_out, int out_size, void* d_ws, size_t ws_size,
                              hipStream_t stream) {
    const float* ctx   = (const float*)d_in[0];
    const float* qry   = (const float*)d_in[1];
    const int*   cmask = (const int*)d_in[2];
    const int*   qmask = (const int*)d_in[3];
    const float* w0    = (const float*)d_in[4];
    float* out = (float*)d_out;

    char* w = (char*)d_ws;
    float* sc      = (float*)w;  w += (long long)65536 * 4;
    float* sq      = (float*)w;  w += (long long)8192 * 4;
    float* rowm    = (float*)w;  w += (long long)65536 * 4;
    float* rowinvl = (float*)w;  w += (long long)65536 * 4;
    float* colm    = (float*)w;  w += (long long)8192 * 4;
    float* colinvl = (float*)w;  w += (long long)8192 * 4;
    float* pm      = (float*)w;  w += (long long)524288 * 4;
    float* pl      = (float*)w;  w += (long long)524288 * 4;
    f16*   sim16   = (f16*)w;    w += (long long)16777216 * 2;
    f16*   ctx16   = (f16*)w;    w += (long long)16777216 * 2;
    f16*   qrywm16 = (f16*)w;    w += (long long)2097152 * 2;
    f16*   Bcat    = (f16*)w;    w += (long long)4194304 * 2;

    k_prep<<<18432, 256, 0, stream>>>(ctx, qry, w0, ctx16, qrywm16, sc, sq);
    k_tq<<<dim3(4, 4, 32), 256, 0, stream>>>(qry, Bcat);
    k_g1<<<dim3(16, 1, 32), 256, 0, stream>>>(ctx16, qrywm16, sc, sq, cmask, qmask, sim16);
    k_s1<<<dim3(64, 32), 256, 0, stream>>>(sim16, rowm, rowinvl, pm, pl);
    k_colreduce<<<32, 256, 0, stream>>>(pm, pl, colm, colinvl);
    k_g3<<<dim3(32, 8), 256, 0, stream>>>(ctx16, sim16, colm, colinvl, Bcat);
    k_g23<<<dim3(16, 4, 32), 256, 0, stream>>>(sim16, rowm, rowinvl, Bcat,
        out, out + (long long)B_ * LC_ * D_);
}